// Round 4
// baseline (101.488 us; speedup 1.0000x reference)
//
#include <hip/hip_runtime.h>

#define NB    32
#define NPB   16384
#define K     2048
#define NF    64
#define NTHR  1024
#define NW    16      // waves per select block
#define KPT   16      // keys per thread (NPB / NTHR)

// Monotone map: float -> uint32 such that float order == unsigned order.
__device__ __forceinline__ unsigned mono(float f) {
  unsigned u = __float_as_uint(f);
  return (u & 0x80000000u) ? ~u : (u | 0x80000000u);
}

// Dense key column: keybuf[b*NPB+i] = mono(in[b,i,0]). Full-grid, HBM-bound.
__global__ __launch_bounds__(256) void extract_keys_kernel(const float* __restrict__ in,
                                                           unsigned* __restrict__ keybuf) {
  int i = blockIdx.x * 256 + threadIdx.x;          // global row in [0, NB*NPB)
  keybuf[i] = mono(in[(size_t)i * NF]);
}

// Per batch (one block): exact radix-select of the rank-K key64 (keys held in
// VGPRs), compact the K winners, bitonic-sort descending, write indices.
// key64(i) = (mono << 32) | ~i  -> desc by value, ties asc by index (== lax.top_k).
__global__ __launch_bounds__(NTHR) void select_sort_kernel(const unsigned* __restrict__ keybuf,
                                                           int* __restrict__ idx_out) {
  __shared__ unsigned hist[256];               // single block histogram
  __shared__ unsigned sfx[257];
  __shared__ unsigned long long wkeys[K];      // 16 KiB
  __shared__ unsigned wbase[NW];
  __shared__ unsigned sh_D, sh_rem;
  __shared__ unsigned long long sh_prefix;

  const int b    = blockIdx.x;
  const int tid  = threadIdx.x;
  const int wid  = tid >> 6;
  const int lane = tid & 63;

  // Hold this thread's 16 key64s in registers. Coalesced loads.
  unsigned long long kreg[KPT];
#pragma unroll
  for (int j = 0; j < KPT; ++j) {
    int i = tid + j * NTHR;
    kreg[j] = ((unsigned long long)keybuf[(size_t)b * NPB + i] << 32) | (unsigned)~(unsigned)i;
  }

  if (tid < 256) hist[tid] = 0;
  if (tid == 0) { sh_rem = K; sh_prefix = 0; }
  __syncthreads();

  // 8 MSB-first radix rounds over key64. Invariant at round entry: hist==0,
  // sh_prefix / sh_rem hold the running threshold prefix and remaining count.
  for (int r = 0; r < 8; ++r) {
    const int shift = 56 - 8 * r;
    const unsigned long long pref = sh_prefix;
    const unsigned rem = sh_rem;

    // Scan registers; wave-aggregated histogram adds (one atomic per distinct
    // bucket per wave-iteration -- immune to value concentration).
#pragma unroll
    for (int j = 0; j < KPT; ++j) {
      bool inclass = (r == 0) || ((kreg[j] >> (shift + 8)) == pref);
      unsigned bkt = (unsigned)(kreg[j] >> shift) & 255u;
      unsigned long long todo = __ballot(inclass);
      while (todo) {
        int leader = __ffsll((unsigned long long)todo) - 1;
        unsigned lb = __shfl(bkt, leader);
        unsigned long long grp = __ballot(inclass && bkt == lb);
        if (lane == leader) atomicAdd(&hist[lb], (unsigned)__popcll(grp));
        todo &= ~grp;
      }
    }
    __syncthreads();

    // Wave 0: inclusive suffix sums of the 256 buckets.
    if (wid == 0) {
      unsigned h0 = hist[4 * lane + 0], h1 = hist[4 * lane + 1];
      unsigned h2 = hist[4 * lane + 2], h3 = hist[4 * lane + 3];
      unsigned s = h0 + h1 + h2 + h3;
      unsigned p = s;                          // inclusive suffix over lanes
      for (int off = 1; off < 64; off <<= 1) {
        unsigned t = __shfl_down(p, off);
        if (lane + off < 64) p += t;
      }
      unsigned run = p - s;                    // sum over lanes > this one
      unsigned s3 = run + h3, s2 = s3 + h2, s1 = s2 + h1, s0 = s1 + h0;
      sfx[4 * lane + 0] = s0; sfx[4 * lane + 1] = s1;
      sfx[4 * lane + 2] = s2; sfx[4 * lane + 3] = s3;
      if (lane == 0) sfx[256] = 0;
    }
    __syncthreads();

    // Find threshold bucket D: count(byte > D) < rem <= count(byte >= D).
    if (tid < 256) {
      unsigned above = sfx[tid + 1];
      if (sfx[tid] >= rem && above < rem) {    // exactly one bucket satisfies
        sh_D = (unsigned)tid;
        sh_rem = rem - above;
        sh_prefix = (pref << 8) | (unsigned)tid;
      }
      hist[tid] = 0;                           // re-zero for next round
    }
    __syncthreads();
  }
  const unsigned long long T = sh_prefix;      // exact rank-K key64

  // Compact winners (key64 >= T -> exactly K of them) via shuffle prefix sums.
  unsigned nw = 0;
#pragma unroll
  for (int j = 0; j < KPT; ++j) nw += (kreg[j] >= T);
  unsigned p = nw;
  for (int off = 1; off < 64; off <<= 1) {
    unsigned t = __shfl_up(p, off);
    if (lane >= off) p += t;
  }
  unsigned excl = p - nw;
  if (lane == 63) wbase[wid] = p;              // wave total
  __syncthreads();
  if (tid == 0) {
    unsigned acc = 0;
    for (int w = 0; w < NW; ++w) { unsigned t = wbase[w]; wbase[w] = acc; acc += t; }
  }
  __syncthreads();
  unsigned pos = wbase[wid] + excl;
#pragma unroll
  for (int j = 0; j < KPT; ++j) {
    if (kreg[j] >= T) wkeys[pos++] = kreg[j];
  }
  __syncthreads();

  // Bitonic sort of the K winners, descending. 1 CE/thread/stage.
  for (int size = 2; size <= K; size <<= 1) {
    for (int stride = size >> 1; stride >= 1; stride >>= 1) {
      int p2 = 2 * tid - (tid & (stride - 1));
      bool desc = ((p2 & size) == 0);
      unsigned long long a = wkeys[p2], bb = wkeys[p2 + stride];
      if (desc ? (a < bb) : (a > bb)) { wkeys[p2] = bb; wkeys[p2 + stride] = a; }
      __syncthreads();
    }
  }

  int* iout = idx_out + (size_t)b * K;
  for (int i = tid; i < K; i += NTHR)
    iout[i] = (int)(~(unsigned)(wkeys[i] & 0xFFFFFFFFull));
}

// Gather the selected rows: one float4 per thread, coalesced 256 B rows.
__global__ __launch_bounds__(256) void gather_kernel(const float* __restrict__ in,
                                                     const int* __restrict__ idx,
                                                     float* __restrict__ out) {
  int tid = blockIdx.x * 256 + threadIdx.x;
  int f4  = tid & 15;               // which float4 of the row
  int row = tid >> 4;               // global output row in [0, NB*K)
  int b   = row >> 11;
  int i   = row & (K - 1);
  int gi  = idx[(size_t)b * K + i];
  const float4* src = reinterpret_cast<const float4*>(in + ((size_t)b * NPB + gi) * NF) + f4;
  float4*       dst = reinterpret_cast<float4*>(out + (size_t)row * NF) + f4;
  *dst = *src;
}

extern "C" void kernel_launch(void* const* d_in, const int* in_sizes, int n_in,
                              void* d_out, int out_size, void* d_ws, size_t ws_size,
                              hipStream_t stream) {
  const float* in = (const float*)d_in[0];
  float* out = (float*)d_out;

  // d_ws layout: [0, 2 MiB) dense keys; [2 MiB, 2.25 MiB) indices.
  unsigned* keybuf = (unsigned*)d_ws;
  int* idx = (int*)((char*)d_ws + (size_t)NB * NPB * sizeof(unsigned));

  extract_keys_kernel<<<(NB * NPB) / 256, 256, 0, stream>>>(in, keybuf);
  select_sort_kernel<<<NB, NTHR, 0, stream>>>(keybuf, idx);
  gather_kernel<<<(NB * K * NF / 4) / 256, 256, 0, stream>>>(in, idx, out);
}

// Round 5
// 70.088 us; speedup vs baseline: 1.4480x; 1.4480x over previous
//
#include <hip/hip_runtime.h>

#define NB    32
#define NPB   16384
#define K     2048
#define NF    64
#define NBINS 8192          // 13-bit bucket = key32 >> 19
#define CAND  4096          // candidate capacity (pow2, >= 2048 + max bin count)
#define NTHR  1024
#define NW    16

// Padded LDS index: breaks power-of-2 stride bank conflicts in the bitonic net.
__device__ __forceinline__ int PAD(int i) { return i + (i >> 5); }

// Monotone map: float -> uint32 such that float order == unsigned order.
__device__ __forceinline__ unsigned mono(float f) {
  unsigned u = __float_as_uint(f);
  return (u & 0x80000000u) ? ~u : (u | 0x80000000u);
}

// 256 blocks (8 per batch): extract key column + per-batch 8192-bin histogram.
__global__ __launch_bounds__(256) void extract_hist_kernel(const float* __restrict__ in,
                                                           unsigned* __restrict__ keybuf,
                                                           unsigned* __restrict__ hist) {
  __shared__ unsigned h[NBINS];                  // 32 KiB
  const int tid = threadIdx.x;
  for (int i = tid; i < NBINS; i += 256) h[i] = 0;
  __syncthreads();

  const int row0 = blockIdx.x * 2048;            // one 2048-row chunk (within a batch)
  const int b = row0 >> 14;
  for (int j = tid; j < 2048; j += 256) {
    int row = row0 + j;
    unsigned k = mono(in[(size_t)row * NF]);
    keybuf[row] = k;
    atomicAdd(&h[k >> 19], 1u);
  }
  __syncthreads();

  unsigned* gh = hist + (size_t)b * NBINS;
  for (int i = tid; i < NBINS; i += 256)
    if (h[i]) atomicAdd(&gh[i], h[i]);
}

// One block per batch: suffix-scan histogram -> bucket threshold, compact
// candidates into LDS, bitonic-sort (padded indices), emit top-K indices.
__global__ __launch_bounds__(NTHR) void select_sort_kernel(const unsigned* __restrict__ keybuf,
                                                           const unsigned* __restrict__ hist,
                                                           int* __restrict__ idx_out) {
  __shared__ unsigned long long cand[CAND + (CAND >> 5)];   // ~33 KiB, padded
  __shared__ unsigned sh_wtot[NW], sh_wsfx[NW];
  __shared__ unsigned sh_floor, sh_cnt;

  const int b    = blockIdx.x;
  const int tid  = threadIdx.x;
  const int wid  = tid >> 6;
  const int lane = tid & 63;

  // ---- 1. Threshold bucket from the histogram (each thread owns 8 bins). ----
  const unsigned* gh = hist + (size_t)b * NBINS;
  const uint4* gh4 = reinterpret_cast<const uint4*>(gh);
  uint4 a0 = gh4[2 * tid], a1 = gh4[2 * tid + 1];
  unsigned hh[8] = {a0.x, a0.y, a0.z, a0.w, a1.x, a1.y, a1.z, a1.w};
  unsigned sum = 0;
#pragma unroll
  for (int j = 0; j < 8; ++j) sum += hh[j];

  // Inclusive suffix scan over lanes (higher lane = higher bins).
  unsigned p = sum;
  for (int off = 1; off < 64; off <<= 1) {
    unsigned t = __shfl_down(p, off);
    if (lane + off < 64) p += t;
  }
  if (lane == 0) sh_wtot[wid] = p;               // wave total
  __syncthreads();
  if (wid == 0) {
    unsigned own = (lane < NW) ? sh_wtot[lane] : 0;
    unsigned p2 = own;
    for (int off = 1; off < NW; off <<= 1) {
      unsigned t = __shfl_down(p2, off);
      if (lane + off < NW) p2 += t;
    }
    if (lane < NW) sh_wsfx[lane] = p2 - own;     // sum over waves above
  }
  __syncthreads();

  unsigned above = sh_wsfx[wid] + (p - sum);     // keys in bins > my chunk
  // Within-chunk suffix sums, find bin D: sfx(D) >= K > sfx(D+1).
  unsigned run = above;
#pragma unroll
  for (int j = 7; j >= 0; --j) {
    unsigned nxt = run;                          // sfx(bin j+1)
    run += hh[j];                                // sfx(bin j)
    if (run >= K && nxt < K) sh_floor = (unsigned)(8 * tid + j) << 19;
  }
  if (tid == 0) sh_cnt = 0;
  // ---- 2. Compact candidates (key32 >= floor) into LDS. ----
  for (int i = tid; i < CAND + (CAND >> 5); i += NTHR) cand[i] = 0;
  __syncthreads();

  const unsigned floor_ = sh_floor;
  const unsigned* kb = keybuf + (size_t)b * NPB;
#pragma unroll
  for (int jj = 0; jj < NPB / NTHR; ++jj) {
    int i = tid + jj * NTHR;
    unsigned k32 = kb[i];
    bool c = (k32 >= floor_);
    unsigned long long mask = __ballot(c);
    if (mask) {
      int leader = __ffsll(mask) - 1;
      unsigned base = 0;
      if (lane == leader) base = atomicAdd(&sh_cnt, (unsigned)__popcll(mask));
      base = __shfl(base, leader);
      unsigned pos = base + (unsigned)__popcll(mask & ((1ull << lane) - 1ull));
      if (c && pos < CAND)
        cand[PAD(pos)] = ((unsigned long long)k32 << 32) | (unsigned)~(unsigned)i;
    }
  }
  __syncthreads();

  // ---- 3. Bitonic sort of CAND entries, descending (padded indices). ----
  for (int size = 2; size <= CAND; size <<= 1) {
    for (int stride = size >> 1; stride >= 1; stride >>= 1) {
#pragma unroll
      for (int e = 0; e < CAND / (2 * NTHR); ++e) {
        int t2 = tid + e * NTHR;
        int pos = 2 * t2 - (t2 & (stride - 1));
        unsigned long long a = cand[PAD(pos)], bb = cand[PAD(pos + stride)];
        bool desc = ((pos & size) == 0);
        if (desc ? (a < bb) : (a > bb)) { cand[PAD(pos)] = bb; cand[PAD(pos + stride)] = a; }
      }
      __syncthreads();
    }
  }

  // ---- 4. Emit top-K indices. ----
  int* iout = idx_out + (size_t)b * K;
  for (int i = tid; i < K; i += NTHR)
    iout[i] = (int)(~(unsigned)(cand[PAD(i)] & 0xFFFFFFFFull));
}

// Gather the selected rows: one float4 per thread, coalesced 256 B rows.
__global__ __launch_bounds__(256) void gather_kernel(const float* __restrict__ in,
                                                     const int* __restrict__ idx,
                                                     float* __restrict__ out) {
  int tid = blockIdx.x * 256 + threadIdx.x;
  int f4  = tid & 15;               // which float4 of the row
  int row = tid >> 4;               // global output row in [0, NB*K)
  int b   = row >> 11;
  int i   = row & (K - 1);
  int gi  = idx[(size_t)b * K + i];
  const float4* src = reinterpret_cast<const float4*>(in + ((size_t)b * NPB + gi) * NF) + f4;
  float4*       dst = reinterpret_cast<float4*>(out + (size_t)row * NF) + f4;
  *dst = *src;
}

extern "C" void kernel_launch(void* const* d_in, const int* in_sizes, int n_in,
                              void* d_out, int out_size, void* d_ws, size_t ws_size,
                              hipStream_t stream) {
  const float* in = (const float*)d_in[0];
  float* out = (float*)d_out;

  // Scratch lives in the front of d_out (16 MiB, fully rewritten by gather):
  //   [0, 2 MiB)      key32 column
  //   [2 MiB, 3 MiB)  per-batch histograms (zeroed each call)
  // d_ws holds the 256 KiB index buffer.
  unsigned* keybuf = (unsigned*)d_out;
  unsigned* hist = (unsigned*)((char*)d_out + (size_t)NB * NPB * sizeof(unsigned));
  int* idx = (int*)d_ws;

  hipMemsetAsync(hist, 0, (size_t)NB * NBINS * sizeof(unsigned), stream);
  extract_hist_kernel<<<NB * NPB / 2048, 256, 0, stream>>>(in, keybuf, hist);
  select_sort_kernel<<<NB, NTHR, 0, stream>>>(keybuf, hist, idx);
  gather_kernel<<<(NB * K * NF / 4) / 256, 256, 0, stream>>>(in, idx, out);
}